// Round 2
// baseline (469.238 us; speedup 1.0000x reference)
//
#include <hip/hip_runtime.h>
#include <stdint.h>

#define N_TOK 4096
#define DIM   256
#define NH    4
#define DH    64
#define TOPK  30
#define CANDN 40      // candidate margin: approx-top-40 superset of exact top-30
#define HWIN  128u    // histogram window in bf16 ulps
#define ATT_SCALE 0.25f
#define LN_EPS 1e-5f

typedef __attribute__((ext_vector_type(8))) short bf16x8;  // 8 bf16 in 4 VGPRs
typedef __attribute__((ext_vector_type(4))) float f32x4;

static __device__ __forceinline__ ushort f2bf(float f) {   // RNE
    uint x = __float_as_uint(f);
    return (ushort)((x + 0x7FFFu + ((x >> 16) & 1u)) >> 16);
}
static __device__ __forceinline__ bf16x8 load_frag(const ushort* p) {
    union { int4 i; bf16x8 f; } u;
    u.i = *reinterpret_cast<const int4*>(p);
    return u.f;
}
static __device__ __forceinline__ uint s16key(uint u) {    // bf16 bits -> sortable u16
    return (u & 0x8000u) ? (u ^ 0xFFFFu) : (u | 0x8000u);
}

// ---------------------------------------------------------------------------
// Fused q+k fp32 GEMM NT (exactness needed for rescoring): for sel in {q,k}:
// out[i][j] = sum_d A[i][d]*W[j][d] + bias[j]. N=512 logical (q cols 0..255,
// k cols 256..511) -> 512 WGs = 2 waves/SIMD.
// ---------------------------------------------------------------------------
#define BK 32
__global__ __launch_bounds__(256) void qk_gemm_f32(
    const float* __restrict__ query_in, const float* __restrict__ key_in,
    const float* __restrict__ Wq, const float* __restrict__ bq,
    const float* __restrict__ Wk, const float* __restrict__ bk,
    float* __restrict__ qf, float* __restrict__ kf,
    ushort* __restrict__ qb, ushort* __restrict__ kb)
{
    const int j0g = blockIdx.x * 64;          // 0..511
    const int sel = j0g >> 8;                 // 0=q, 1=k
    const int j0  = j0g & 255;
    const float* A    = sel ? key_in : query_in;
    const float* W    = sel ? Wk : Wq;
    const float* bias = sel ? bk : bq;
    float*  outF = sel ? kf : qf;
    ushort* outB = sel ? kb : qb;

    __shared__ float As[BK][64 + 4];
    __shared__ float Ws[BK][64 + 4];
    const int tid = threadIdx.x;
    const int tx = tid & 15;
    const int ty = tid >> 4;
    const int i0 = blockIdx.y * 64;

    float acc[4][4];
#pragma unroll
    for (int r = 0; r < 4; r++)
#pragma unroll
        for (int c = 0; c < 4; c++) acc[r][c] = 0.f;

    for (int k0 = 0; k0 < DIM; k0 += BK) {
#pragma unroll
        for (int u = 0; u < 2; u++) {
            const int f = u * 256 + tid;
            const int r = f >> 3;
            const int c = (f & 7) * 4;
            float4 va = *reinterpret_cast<const float4*>(A + (size_t)(i0 + r) * DIM + k0 + c);
            As[c + 0][r] = va.x; As[c + 1][r] = va.y;
            As[c + 2][r] = va.z; As[c + 3][r] = va.w;
            float4 vw = *reinterpret_cast<const float4*>(W + (size_t)(j0 + r) * DIM + k0 + c);
            Ws[c + 0][r] = vw.x; Ws[c + 1][r] = vw.y;
            Ws[c + 2][r] = vw.z; Ws[c + 3][r] = vw.w;
        }
        __syncthreads();
#pragma unroll
        for (int kk = 0; kk < BK; kk++) {
            const float4 a4 = *reinterpret_cast<const float4*>(&As[kk][ty * 4]);
            const float4 b4 = *reinterpret_cast<const float4*>(&Ws[kk][tx * 4]);
            const float ar[4] = {a4.x, a4.y, a4.z, a4.w};
            const float br[4] = {b4.x, b4.y, b4.z, b4.w};
#pragma unroll
            for (int r = 0; r < 4; r++)
#pragma unroll
                for (int c = 0; c < 4; c++) acc[r][c] += ar[r] * br[c];
        }
        __syncthreads();
    }

#pragma unroll
    for (int r = 0; r < 4; r++) {
        const int gi = i0 + ty * 4 + r;
#pragma unroll
        for (int c = 0; c < 4; c++) {
            const int gj = j0 + tx * 4 + c;
            float v = acc[r][c] + bias[gj];
            outF[(size_t)gi * DIM + gj] = v;
            outB[(size_t)gi * DIM + gj] = f2bf(v);
        }
    }
}

// ---------------------------------------------------------------------------
// Cast fp32 -> bf16: value_in (1M), Wv (64K), Wo (64K), one linear kernel.
// ---------------------------------------------------------------------------
__global__ __launch_bounds__(256) void cast_kernel(
    const float* __restrict__ value_in, const float* __restrict__ Wv,
    const float* __restrict__ Wo, ushort* __restrict__ value_b,
    ushort* __restrict__ Wv_b, ushort* __restrict__ Wo_b)
{
    const int id4 = blockIdx.x * 256 + threadIdx.x;   // one float4 per thread
    const int NV = 1048576 / 4, NW = 65536 / 4;
    const float* src; ushort* dst; int off;
    if (id4 < NV)            { src = value_in; dst = value_b; off = id4; }
    else if (id4 < NV + NW)  { src = Wv; dst = Wv_b; off = id4 - NV; }
    else                     { src = Wo; dst = Wo_b; off = id4 - NV - NW; }
    float4 v = reinterpret_cast<const float4*>(src)[off];
    ushort4 o = {f2bf(v.x), f2bf(v.y), f2bf(v.z), f2bf(v.w)};
    reinterpret_cast<ushort4*>(dst)[off] = o;
}

// ---------------------------------------------------------------------------
// bf16 MFMA GEMM NT: out[i][j] = sum_d A[i][d]*B[j][d] + bias[j] (+addX).
// M=4096, N=256, K=256. Grid (4,64): wave = 16 rows x 64 cols.
// ---------------------------------------------------------------------------
__global__ __launch_bounds__(256) void mfma_gemm(
    const ushort* __restrict__ A, const ushort* __restrict__ B,
    const float* __restrict__ bias, const float* __restrict__ addX,
    float* __restrict__ outF)
{
    const int lane = threadIdx.x & 63;
    const int wv   = threadIdx.x >> 6;
    const int i0   = blockIdx.y * 64 + wv * 16;
    const int j0   = blockIdx.x * 64;
    const int r = lane & 15, q = lane >> 4;

    f32x4 acc[4];
#pragma unroll
    for (int b = 0; b < 4; b++) acc[b] = (f32x4){0.f, 0.f, 0.f, 0.f};

#pragma unroll
    for (int ks = 0; ks < 8; ks++) {
        const int kk = ks * 32 + q * 8;
        bf16x8 af = load_frag(A + (size_t)(i0 + r) * DIM + kk);
        bf16x8 bfr[4];
#pragma unroll
        for (int jt = 0; jt < 4; jt++)
            bfr[jt] = load_frag(B + (size_t)(j0 + jt * 16 + r) * DIM + kk);
#pragma unroll
        for (int jt = 0; jt < 4; jt++)
            acc[jt] = __builtin_amdgcn_mfma_f32_16x16x32_bf16(af, bfr[jt], acc[jt], 0, 0, 0);
    }

#pragma unroll
    for (int jt = 0; jt < 4; jt++) {
        const int gj = j0 + jt * 16 + r;          // col = lane&15
        const float bv = bias[gj];
#pragma unroll
        for (int rg = 0; rg < 4; rg++) {          // row = (lane>>4)*4+reg
            const int gi = i0 + q * 4 + rg;
            float v = acc[jt][rg] + bv;
            if (addX) v += addX[(size_t)gi * DIM + gj];
            outF[(size_t)gi * DIM + gj] = v;
        }
    }
}

// ---------------------------------------------------------------------------
// FUSED scores+select: one block = 1024 thr (16 waves) = 16 query rows x one
// head x ALL 4096 key cols. Phase 1: operand-swapped MFMA mfma(K,Q) so each
// lane holds 4 consecutive k-cols of ONE q-row -> one ds_write_b64 of packed
// sortable u16 keys into a 128 KB LDS tile [16][4096], XOR-swizzled
// (byte ^= (row&7)<<4) so the 16-lane/row write spreads over 8 banks-groups
// and the per-row phase-2 read stays conflict-free (row uniform per wave).
// Phase 2: wave w = row w: histogram window / prefix scan / exact fp32
// rescore / bitonic / softmax / ctx, all as before but reading LDS not HBM.
// Eliminates the 256 MB sb HBM round-trip entirely.
// ---------------------------------------------------------------------------
__global__ __launch_bounds__(1024) void fused_scores_select(
    const ushort* __restrict__ qb, const ushort* __restrict__ kb,
    const float* __restrict__ qf, const float* __restrict__ kf,
    const float* __restrict__ vf,
    float* __restrict__ pval, int* __restrict__ pidx,
    ushort* __restrict__ ctxb)
{
    const int lane = threadIdx.x & 63;
    const int wv   = threadIdx.x >> 6;       // 0..15
    const int h    = blockIdx.y;
    const int i0   = blockIdx.x * 16;
    const int r = lane & 15, q = lane >> 4;
    const int koff = h * DH;

    __shared__ __align__(16) ushort sc[16][4096];   // 128 KB
    __shared__ uint  hist[16][HWIN];
    __shared__ uint  cand[16][64];
    __shared__ uint  ccnt[16];
    __shared__ float pw[16][TOPK];
    __shared__ int   jw[16][TOPK];
    __shared__ __align__(16) float qsh[16][DH];

    char* const scb = reinterpret_cast<char*>(&sc[0][0]);

    // ---- phase 1: 16x256 score stripe per wave -> swizzled u16 keys in LDS
    const bf16x8 bq0 = load_frag(qb + (size_t)(i0 + r) * DIM + koff + q * 8);
    const bf16x8 bq1 = load_frag(qb + (size_t)(i0 + r) * DIM + koff + 32 + q * 8);
    const uint wswz  = ((uint)(r & 7)) << 4;
    const uint wbase = (uint)r * 8192u;
#pragma unroll
    for (int jt = 0; jt < 16; jt++) {
        const int jbase = wv * 256 + jt * 16;
        bf16x8 ka0 = load_frag(kb + (size_t)(jbase + r) * DIM + koff + q * 8);
        bf16x8 ka1 = load_frag(kb + (size_t)(jbase + r) * DIM + koff + 32 + q * 8);
        f32x4 acc = (f32x4){0.f, 0.f, 0.f, 0.f};
        acc = __builtin_amdgcn_mfma_f32_16x16x32_bf16(ka0, bq0, acc, 0, 0, 0);
        acc = __builtin_amdgcn_mfma_f32_16x16x32_bf16(ka1, bq1, acc, 0, 0, 0);
        // lane holds scores for q-row (i0+r), k-cols jbase+q*4+{0..3}
        const uint k0 = s16key(f2bf(acc[0])), k1 = s16key(f2bf(acc[1]));
        const uint k2 = s16key(f2bf(acc[2])), k3 = s16key(f2bf(acc[3]));
        uint2 two; two.x = k0 | (k1 << 16); two.y = k2 | (k3 << 16);
        const uint e2 = (uint)((jbase + q * 4) * 2);
        *reinterpret_cast<uint2*>(scb + (wbase + (e2 ^ wswz))) = two;
    }

    qsh[wv][lane] = qf[(size_t)(i0 + wv) * DIM + koff + lane];
    hist[wv][lane] = 0u; hist[wv][64 + lane] = 0u;
    if (lane == 0) ccnt[wv] = 0u;
    __syncthreads();

    // ---- phase 2: wave wv owns row (i0+wv)
    const int grow = i0 + wv;
    const int orow = h * N_TOK + grow;
    const uint rswz = ((uint)(wv & 7)) << 4;
    char* const rowb = scb + (size_t)wv * 8192;

    uint kw[32];
#pragma unroll
    for (int t = 0; t < 8; t++) {
        int4 c = *reinterpret_cast<const int4*>(
            rowb + (((uint)(t * 1024 + lane * 16)) ^ rswz));
        kw[t * 4 + 0] = (uint)c.x; kw[t * 4 + 1] = (uint)c.y;
        kw[t * 4 + 2] = (uint)c.z; kw[t * 4 + 3] = (uint)c.w;
    }

    uint mx = 0;
#pragma unroll
    for (int w = 0; w < 32; w++) {
        uint lo16 = kw[w] & 0xFFFFu, hi16 = kw[w] >> 16;
        mx = max(mx, max(lo16, hi16));
    }
#pragma unroll
    for (int off = 32; off; off >>= 1)
        mx = max(mx, (uint)__shfl_xor((int)mx, off));

#pragma unroll
    for (int w = 0; w < 32; w++) {
        uint d0 = mx - (kw[w] & 0xFFFFu);
        uint d1 = mx - (kw[w] >> 16);
        if (d0 < HWIN) atomicAdd(&hist[wv][d0], 1u);
        if (d1 < HWIN) atomicAdd(&hist[wv][d1], 1u);
    }
    __builtin_amdgcn_wave_barrier();

    const uint c0 = hist[wv][lane * 2 + 0];
    const uint c1 = hist[wv][lane * 2 + 1];
    const uint seg = c0 + c1;
    uint scan = seg;
#pragma unroll
    for (int d = 1; d < 64; d <<= 1) {
        uint y = (uint)__shfl_up((int)scan, d);
        if (lane >= d) scan += y;
    }
    const uint excl = scan - seg;
    const bool crossing = (excl < CANDN) && (scan >= CANDN);
    unsigned long long bal = __ballot(crossing);

    int t = 256;
    if (bal != 0ull) {
        const int srcLane = __ffsll(bal) - 1;
        int tloc = lane * 2;
        if (crossing) {
            uint cum = excl + c0;
            if (cum < CANDN) tloc++;
        }
        t = __shfl(tloc, srcLane);
    }

    uint T;
    if (t <= 254) {
        T = mx - (uint)t;
    } else {
        // exact fallback: top-40 spread exceeds HWIN ulps (rare)
        uint lo = 0;
#pragma unroll
        for (int b = 15; b >= 0; b--) {
            uint trial = lo | (1u << b);
            int c = 0;
#pragma unroll
            for (int w = 0; w < 32; w++) {
                c += ((kw[w] & 0xFFFFu) >= trial) ? 1 : 0;
                c += ((kw[w] >> 16)     >= trial) ? 1 : 0;
            }
#pragma unroll
            for (int off = 32; off; off >>= 1) c += __shfl_xor(c, off);
            if (c >= CANDN) lo = trial;
        }
        T = lo;
    }

#pragma unroll
    for (int w = 0; w < 32; w++) {
        const uint lo16 = kw[w] & 0xFFFFu, hi16 = kw[w] >> 16;
        const int j0c = (w >> 2) * 512 + lane * 8 + (w & 3) * 2;  // = k column
        if (lo16 >= T) {
            uint pos = atomicAdd(&ccnt[wv], 1u);
            if (pos < 64u) cand[wv][pos] = (uint)j0c;
        }
        if (hi16 >= T) {
            uint pos = atomicAdd(&ccnt[wv], 1u);
            if (pos < 64u) cand[wv][pos] = (uint)(j0c + 1);
        }
    }
    __builtin_amdgcn_wave_barrier();
    const int m = (int)min(ccnt[wv], 64u);

    unsigned long long ukey = 0ull;
    if (lane < m) {
        const int j = (int)cand[wv][lane];
        const float4* kr = reinterpret_cast<const float4*>(kf + (size_t)j * DIM + koff);
        const float4* qr = reinterpret_cast<const float4*>(qsh[wv]);
        float s = 0.f;
#pragma unroll
        for (int d = 0; d < 16; d++) {
            float4 a = qr[d], bb = kr[d];
            s += a.x * bb.x; s += a.y * bb.y; s += a.z * bb.z; s += a.w * bb.w;
        }
        uint bits = __float_as_uint(s);
        uint s32 = (bits & 0x80000000u) ? ~bits : (bits | 0x80000000u);
        ukey = ((unsigned long long)s32 << 12) | (unsigned long long)(4095 - j);
    }

#pragma unroll
    for (int k = 2; k <= 64; k <<= 1) {
#pragma unroll
        for (int jj = k >> 1; jj > 0; jj >>= 1) {
            unsigned long long o = __shfl_xor(ukey, jj);
            bool keepMax = ((lane & jj) != 0) ^ ((lane & k) != 0);
            ukey = keepMax ? (ukey > o ? ukey : o) : (ukey < o ? ukey : o);
        }
    }

    const int rank = 63 - lane;
    const int jsel = 4095 - (int)(ukey & 0xFFFull);
    uint s32b = (uint)(ukey >> 12);
    uint fb = (s32b & 0x80000000u) ? (s32b ^ 0x80000000u) : ~s32b;
    const float sc2 = __uint_as_float(fb);
    const float stop = __shfl(sc2, 63);

    float e = (rank < TOPK) ? __expf((sc2 - stop) * ATT_SCALE) : 0.f;
    float esum = e;
#pragma unroll
    for (int off = 32; off; off >>= 1) esum += __shfl_xor(esum, off);
    const float p = e / esum;

    if (rank < TOPK) {
        pw[wv][rank] = p; jw[wv][rank] = jsel;
        pval[(size_t)orow * 32 + rank] = p;
        pidx[(size_t)orow * 32 + rank] = jsel;
    }
    __builtin_amdgcn_wave_barrier();

    float a = 0.f;
#pragma unroll
    for (int c = 0; c < TOPK; c++)
        a += pw[wv][c] * vf[(size_t)jw[wv][c] * DIM + koff + lane];
    ctxb[(size_t)grow * DIM + koff + lane] = f2bf(a);
}

// ---------------------------------------------------------------------------
// attn_write v2: 4 rows per block, LDS-staged (zero + scatter in LDS, one
// global write pass).
// ---------------------------------------------------------------------------
__global__ __launch_bounds__(256) void attn_write(
    const float* __restrict__ pval, const int* __restrict__ pidx,
    float* __restrict__ attnF)
{
    __shared__ __align__(16) float rb[4][N_TOK];
    const int tid = threadIdx.x;
    const int r0 = blockIdx.x * 4;

    float4* rb4 = reinterpret_cast<float4*>(&rb[0][0]);
    const float4 z = {0.f, 0.f, 0.f, 0.f};
#pragma unroll
    for (int t = 0; t < 16; t++) rb4[t * 256 + tid] = z;
    __syncthreads();
    if (tid < 4 * TOPK) {
        const int w = tid / TOPK, c = tid % TOPK;
        rb[w][pidx[(size_t)(r0 + w) * 32 + c]] = pval[(size_t)(r0 + w) * 32 + c];
    }
    __syncthreads();
#pragma unroll
    for (int w = 0; w < 4; w++) {
        float4* grow = reinterpret_cast<float4*>(attnF + (size_t)(r0 + w) * N_TOK);
#pragma unroll
        for (int t = 0; t < 4; t++)
            grow[t * 256 + tid] = rb4[w * 1024 + t * 256 + tid];
    }
}

// ---------------------------------------------------------------------------
// Row LayerNorm (biased var), in-place on fp32 resid. One wave per row.
// ---------------------------------------------------------------------------
__global__ __launch_bounds__(64) void ln_kernel(
    float* __restrict__ resb, const float* __restrict__ g,
    const float* __restrict__ b)
{
    const int i = blockIdx.x, lane = threadIdx.x;
    float4* rowp = reinterpret_cast<float4*>(resb + (size_t)i * DIM);
    float4 x = rowp[lane];
    float s  = x.x + x.y + x.z + x.w;
    float sq = x.x * x.x + x.y * x.y + x.z * x.z + x.w * x.w;
#pragma unroll
    for (int off = 32; off; off >>= 1) {
        s  += __shfl_xor(s, off);
        sq += __shfl_xor(sq, off);
    }
    const float mu  = s * (1.f / DIM);
    const float var = sq * (1.f / DIM) - mu * mu;
    const float rstd = rsqrtf(var + LN_EPS);
    const int col = lane * 4;
    float4 o;
    o.x = (x.x - mu) * rstd * g[col + 0] + b[col + 0];
    o.y = (x.y - mu) * rstd * g[col + 1] + b[col + 1];
    o.z = (x.z - mu) * rstd * g[col + 2] + b[col + 2];
    o.w = (x.w - mu) * rstd * g[col + 3] + b[col + 3];
    rowp[lane] = o;
}

// ---------------------------------------------------------------------------
extern "C" void kernel_launch(void* const* d_in, const int* in_sizes, int n_in,
                              void* d_out, int out_size, void* d_ws, size_t ws_size,
                              hipStream_t stream)
{
    const float* key_in   = (const float*)d_in[0];
    const float* value_in = (const float*)d_in[1];
    const float* query_in = (const float*)d_in[2];
    const float* Wq = (const float*)d_in[3];
    const float* bq = (const float*)d_in[4];
    const float* Wk = (const float*)d_in[5];
    const float* bk = (const float*)d_in[6];
    const float* Wv = (const float*)d_in[7];
    const float* bv = (const float*)d_in[8];
    const float* Wo = (const float*)d_in[9];
    const float* bo = (const float*)d_in[10];
    const float* ln_g = (const float*)d_in[11];
    const float* ln_b = (const float*)d_in[12];

    float* outF  = (float*)d_out;                     // (N, D) fp32
    float* attnF = outF + (size_t)N_TOK * DIM;        // (H, N, N) fp32

    // Scratch carved inside the attn output region (all consumed before
    // attn_write overwrites it; attn_write runs last). sb is GONE (fused
    // kernel keeps scores in LDS).
    const size_t SC = 33554432;
    float*  qf   = attnF + SC;
    float*  kf   = attnF + SC + 1048576;
    float*  vf   = attnF + SC + 2097152;
    ushort* qb   = (ushort*)(attnF + SC + 3145728);
    ushort* kb   = (ushort*)(attnF + SC + 3670016);
    ushort* ctxb = (ushort*)(attnF + SC + 4194304);

    // d_ws: pval/pidx + bf16 casts (~6.3 MB)
    float*  pval    = (float*)d_ws;                     // 2 MB
    int*    pidx    = (int*)d_ws + 524288;              // 2 MB
    ushort* value_b = (ushort*)((char*)d_ws + (4u << 20));   // 2 MB
    ushort* Wv_b    = (ushort*)((char*)d_ws + (6u << 20));   // 128 KB
    ushort* Wo_b    = (ushort*)((char*)d_ws + (6u << 20) + 131072);

    cast_kernel<<<dim3((1048576 + 65536 + 65536) / 4 / 256), 256, 0, stream>>>(
        value_in, Wv, Wo, value_b, Wv_b, Wo_b);
    qk_gemm_f32<<<dim3(8, 64), 256, 0, stream>>>(
        query_in, key_in, Wq, bq, Wk, bk, qf, kf, qb, kb);
    mfma_gemm<<<dim3(4, 64), 256, 0, stream>>>(value_b, Wv_b, bv, nullptr, vf);

    fused_scores_select<<<dim3(N_TOK / 16, NH), 1024, 0, stream>>>(
        qb, kb, qf, kf, vf, pval, pidx, ctxb);

    mfma_gemm<<<dim3(4, 64), 256, 0, stream>>>(ctxb, Wo_b, bo, query_in, outF);
    ln_kernel<<<N_TOK, 64, 0, stream>>>(outF, ln_g, ln_b);

    attn_write<<<N_TOK * NH / 4, 256, 0, stream>>>(pval, pidx, attnF);
}

// Round 3
// 438.977 us; speedup vs baseline: 1.0689x; 1.0689x over previous
//
#include <hip/hip_runtime.h>
#include <stdint.h>

#define N_TOK 4096
#define DIM   256
#define NH    4
#define DH    64
#define TOPK  30
#define CANDN 40      // candidate margin: approx-top-40 superset of exact top-30
#define HWIN  128u    // histogram window in bf16 ulps
#define ATT_SCALE 0.25f
#define LN_EPS 1e-5f

typedef __attribute__((ext_vector_type(8))) short bf16x8;  // 8 bf16 in 4 VGPRs
typedef __attribute__((ext_vector_type(4))) float f32x4;

static __device__ __forceinline__ ushort f2bf(float f) {   // RNE
    uint x = __float_as_uint(f);
    return (ushort)((x + 0x7FFFu + ((x >> 16) & 1u)) >> 16);
}
static __device__ __forceinline__ bf16x8 load_frag(const ushort* p) {
    union { int4 i; bf16x8 f; } u;
    u.i = *reinterpret_cast<const int4*>(p);
    return u.f;
}
// fp32 -> bf16 fragment conversion in-register (same RNE as cast_kernel did;
// bit-identical pipeline, one fewer kernel).
static __device__ __forceinline__ bf16x8 cvt_frag(const float* p) {
    float4 a = *reinterpret_cast<const float4*>(p);
    float4 b = *reinterpret_cast<const float4*>(p + 4);
    union { ushort u[8]; bf16x8 f; } u;
    u.u[0] = f2bf(a.x); u.u[1] = f2bf(a.y); u.u[2] = f2bf(a.z); u.u[3] = f2bf(a.w);
    u.u[4] = f2bf(b.x); u.u[5] = f2bf(b.y); u.u[6] = f2bf(b.z); u.u[7] = f2bf(b.w);
    return u.f;
}
static __device__ __forceinline__ uint s16key(uint u) {    // bf16 bits -> sortable u16
    return (u & 0x8000u) ? (u ^ 0xFFFFu) : (u | 0x8000u);
}
// sb row layout: u16 position P (0..4095) -> column j (see scores_kernel).
static __device__ __forceinline__ int jdecode(int P) {
    return (P & ~127) | ((P & 7) << 4) | ((P >> 3) & 15);
}

// ---------------------------------------------------------------------------
// front_kernel: merged launch.
//   blockIdx.x in [0,8):  fused q+k fp32 GEMM NT (exact, for rescoring):
//       out[i][j] = sum_d A[i][d]*W[j][d] + bias[j]; q cols 0..255 (bx 0..3),
//       k cols 256..511 (bx 4..7).
//   blockIdx.x in [8,12): v-projection bf16 MFMA GEMM NT, fp32 operands
//       converted to bf16 in-register (bit-identical to prior cast+mfma).
// ---------------------------------------------------------------------------
#define BK 32
__global__ __launch_bounds__(256) void front_kernel(
    const float* __restrict__ query_in, const float* __restrict__ key_in,
    const float* __restrict__ value_in,
    const float* __restrict__ Wq, const float* __restrict__ bq,
    const float* __restrict__ Wk, const float* __restrict__ bk,
    const float* __restrict__ Wv, const float* __restrict__ bv,
    float* __restrict__ qf, float* __restrict__ kf,
    ushort* __restrict__ qb, ushort* __restrict__ kb,
    float* __restrict__ vf)
{
    if (blockIdx.x < 8) {
        // ---- fp32 q/k projection (exactness needed for rescore) ----
        const int j0g = blockIdx.x * 64;          // 0..511
        const int sel = j0g >> 8;                 // 0=q, 1=k
        const int j0  = j0g & 255;
        const float* A    = sel ? key_in : query_in;
        const float* W    = sel ? Wk : Wq;
        const float* bias = sel ? bk : bq;
        float*  outF = sel ? kf : qf;
        ushort* outB = sel ? kb : qb;

        __shared__ float As[BK][64 + 4];
        __shared__ float Ws[BK][64 + 4];
        const int tid = threadIdx.x;
        const int tx = tid & 15;
        const int ty = tid >> 4;
        const int i0 = blockIdx.y * 64;

        float acc[4][4];
#pragma unroll
        for (int r = 0; r < 4; r++)
#pragma unroll
            for (int c = 0; c < 4; c++) acc[r][c] = 0.f;

        for (int k0 = 0; k0 < DIM; k0 += BK) {
#pragma unroll
            for (int u = 0; u < 2; u++) {
                const int f = u * 256 + tid;
                const int r = f >> 3;
                const int c = (f & 7) * 4;
                float4 va = *reinterpret_cast<const float4*>(A + (size_t)(i0 + r) * DIM + k0 + c);
                As[c + 0][r] = va.x; As[c + 1][r] = va.y;
                As[c + 2][r] = va.z; As[c + 3][r] = va.w;
                float4 vw = *reinterpret_cast<const float4*>(W + (size_t)(j0 + r) * DIM + k0 + c);
                Ws[c + 0][r] = vw.x; Ws[c + 1][r] = vw.y;
                Ws[c + 2][r] = vw.z; Ws[c + 3][r] = vw.w;
            }
            __syncthreads();
#pragma unroll
            for (int kk = 0; kk < BK; kk++) {
                const float4 a4 = *reinterpret_cast<const float4*>(&As[kk][ty * 4]);
                const float4 b4 = *reinterpret_cast<const float4*>(&Ws[kk][tx * 4]);
                const float ar[4] = {a4.x, a4.y, a4.z, a4.w};
                const float br[4] = {b4.x, b4.y, b4.z, b4.w};
#pragma unroll
                for (int r = 0; r < 4; r++)
#pragma unroll
                    for (int c = 0; c < 4; c++) acc[r][c] += ar[r] * br[c];
            }
            __syncthreads();
        }

#pragma unroll
        for (int r = 0; r < 4; r++) {
            const int gi = i0 + ty * 4 + r;
#pragma unroll
            for (int c = 0; c < 4; c++) {
                const int gj = j0 + tx * 4 + c;
                float v = acc[r][c] + bias[gj];
                outF[(size_t)gi * DIM + gj] = v;
                outB[(size_t)gi * DIM + gj] = f2bf(v);
            }
        }
    } else {
        // ---- v-projection: bf16 MFMA, operands converted in-register ----
        const int lane = threadIdx.x & 63;
        const int wv   = threadIdx.x >> 6;
        const int i0   = blockIdx.y * 64 + wv * 16;
        const int j0   = (blockIdx.x - 8) * 64;
        const int r = lane & 15, q = lane >> 4;

        f32x4 acc[4];
#pragma unroll
        for (int b = 0; b < 4; b++) acc[b] = (f32x4){0.f, 0.f, 0.f, 0.f};

#pragma unroll
        for (int ks = 0; ks < 8; ks++) {
            const int kk = ks * 32 + q * 8;
            bf16x8 af = cvt_frag(value_in + (size_t)(i0 + r) * DIM + kk);
            bf16x8 bfr[4];
#pragma unroll
            for (int jt = 0; jt < 4; jt++)
                bfr[jt] = cvt_frag(Wv + (size_t)(j0 + jt * 16 + r) * DIM + kk);
#pragma unroll
            for (int jt = 0; jt < 4; jt++)
                acc[jt] = __builtin_amdgcn_mfma_f32_16x16x32_bf16(af, bfr[jt], acc[jt], 0, 0, 0);
        }

#pragma unroll
        for (int jt = 0; jt < 4; jt++) {
            const int gj = j0 + jt * 16 + r;          // col = lane&15
            const float bvv = bv[gj];
#pragma unroll
            for (int rg = 0; rg < 4; rg++) {          // row = (lane>>4)*4+reg
                const int gi = i0 + q * 4 + rg;
                vf[(size_t)gi * DIM + gj] = acc[jt][rg] + bvv;
            }
        }
    }
}

// ---------------------------------------------------------------------------
// Out-projection bf16 MFMA GEMM NT: A = ctxb (bf16), B = Wo (fp32, converted
// in-register), out = A@B^T + bo + query_in (residual). Grid (4,64).
// ---------------------------------------------------------------------------
__global__ __launch_bounds__(256) void oproj_kernel(
    const ushort* __restrict__ A, const float* __restrict__ Wo,
    const float* __restrict__ bias, const float* __restrict__ addX,
    float* __restrict__ outF)
{
    const int lane = threadIdx.x & 63;
    const int wv   = threadIdx.x >> 6;
    const int i0   = blockIdx.y * 64 + wv * 16;
    const int j0   = blockIdx.x * 64;
    const int r = lane & 15, q = lane >> 4;

    f32x4 acc[4];
#pragma unroll
    for (int b = 0; b < 4; b++) acc[b] = (f32x4){0.f, 0.f, 0.f, 0.f};

#pragma unroll
    for (int ks = 0; ks < 8; ks++) {
        const int kk = ks * 32 + q * 8;
        bf16x8 af = load_frag(A + (size_t)(i0 + r) * DIM + kk);
        bf16x8 bfr[4];
#pragma unroll
        for (int jt = 0; jt < 4; jt++)
            bfr[jt] = cvt_frag(Wo + (size_t)(j0 + jt * 16 + r) * DIM + kk);
#pragma unroll
        for (int jt = 0; jt < 4; jt++)
            acc[jt] = __builtin_amdgcn_mfma_f32_16x16x32_bf16(af, bfr[jt], acc[jt], 0, 0, 0);
    }

#pragma unroll
    for (int jt = 0; jt < 4; jt++) {
        const int gj = j0 + jt * 16 + r;
        const float bvv = bias[gj];
#pragma unroll
        for (int rg = 0; rg < 4; rg++) {
            const int gi = i0 + q * 4 + rg;
            float v = acc[jt][rg] + bvv + addX[(size_t)gi * DIM + gj];
            outF[(size_t)gi * DIM + gj] = v;
        }
    }
}

// ---------------------------------------------------------------------------
// Approx scores (bf16 q/k via MFMA, fp32 accum) stored as SORTABLE U16 KEYS
// into sb, PACKED in fragment-natural order (see jdecode): per lane one int4
// store per (mt,rg) -> 8 store instrs/lane, 256 B contiguous segments.
// ---------------------------------------------------------------------------
__global__ __launch_bounds__(256) void scores_kernel(
    const ushort* __restrict__ qb, const ushort* __restrict__ kb,
    ushort* __restrict__ sb)
{
    const int lane = threadIdx.x & 63;
    const int wv   = threadIdx.x >> 6;
    const int h    = blockIdx.z;
    const int i0   = blockIdx.y * 128 + wv * 32;
    const int j0   = blockIdx.x * 128;
    const int r = lane & 15, q = lane >> 4;
    const int koff = h * DH;

    f32x4 acc[2][8];
#pragma unroll
    for (int a = 0; a < 2; a++)
#pragma unroll
        for (int b = 0; b < 8; b++) acc[a][b] = (f32x4){0.f, 0.f, 0.f, 0.f};

#pragma unroll
    for (int ks = 0; ks < 2; ks++) {
        const int kk = koff + ks * 32 + q * 8;
        bf16x8 af[2], bfr[8];
#pragma unroll
        for (int mt = 0; mt < 2; mt++)
            af[mt] = load_frag(qb + (size_t)(i0 + mt * 16 + r) * DIM + kk);
#pragma unroll
        for (int jt = 0; jt < 8; jt++)
            bfr[jt] = load_frag(kb + (size_t)(j0 + jt * 16 + r) * DIM + kk);
#pragma unroll
        for (int mt = 0; mt < 2; mt++)
#pragma unroll
            for (int jt = 0; jt < 8; jt++)
                acc[mt][jt] = __builtin_amdgcn_mfma_f32_16x16x32_bf16(
                    af[mt], bfr[jt], acc[mt][jt], 0, 0, 0);
    }

    const int tileBase = (j0 >> 7) * 16;          // int4 index of this col-tile
#pragma unroll
    for (int mt = 0; mt < 2; mt++)
#pragma unroll
        for (int rg = 0; rg < 4; rg++) {
            const int gi = i0 + mt * 16 + q * 4 + rg;   // C: row=(lane>>4)*4+reg
            uint w4[4];
#pragma unroll
            for (int p = 0; p < 4; p++) {
                const uint klo = s16key(f2bf(acc[mt][2 * p + 0][rg]));
                const uint khi = s16key(f2bf(acc[mt][2 * p + 1][rg]));
                w4[p] = klo | (khi << 16);
            }
            int4 outv;
            outv.x = (int)w4[0]; outv.y = (int)w4[1];
            outv.z = (int)w4[2]; outv.w = (int)w4[3];
            int4* rowp = reinterpret_cast<int4*>(sb + ((size_t)(h * N_TOK + gi)) * N_TOK);
            rowp[tileBase + r] = outv;
        }
}

// ---------------------------------------------------------------------------
// Selection. 4 rows per 256-thr block. Histogram keys within HWIN ulps of
// row max; prefix-scan to rank-40 bin edge; exact fp32 rescore; bitonic
// sort; softmax; emits (idx,prob) + bf16 ctx.
// ---------------------------------------------------------------------------
__global__ __launch_bounds__(256) void select_kernel(
    const ushort* __restrict__ sb, const float* __restrict__ qf,
    const float* __restrict__ kf, const float* __restrict__ vf,
    float* __restrict__ pval, int* __restrict__ pidx,
    ushort* __restrict__ ctxb)
{
    const int lane = threadIdx.x & 63;
    const int wv   = threadIdx.x >> 6;
    const int row  = blockIdx.x * 4 + wv;      // 0..16383
    const int h    = row >> 12;
    const int i    = row & (N_TOK - 1);
    const ushort* srow = sb + (size_t)row * N_TOK;

    __shared__ uint  hist[4][256];
    __shared__ uint  cand[4][64];
    __shared__ uint  ccnt[4];
    __shared__ float pw[4][TOPK];
    __shared__ int   jw[4][TOPK];
    __shared__ __align__(16) float qsh[4][DH];

    qsh[wv][lane] = qf[(size_t)i * DIM + h * DH + lane];
    if (lane == 0) ccnt[wv] = 0;
#pragma unroll
    for (int b = 0; b < 4; b++) hist[wv][b * 64 + lane] = 0u;  // stride-64: free

    uint kw[32];
    const int4* srow4 = reinterpret_cast<const int4*>(srow);
#pragma unroll
    for (int t = 0; t < 8; t++) {
        int4 c = srow4[t * 64 + lane];
        kw[t * 4 + 0] = (uint)c.x; kw[t * 4 + 1] = (uint)c.y;
        kw[t * 4 + 2] = (uint)c.z; kw[t * 4 + 3] = (uint)c.w;
    }

    uint mx = 0;
#pragma unroll
    for (int w = 0; w < 32; w++) {
        uint lo16 = kw[w] & 0xFFFFu, hi16 = kw[w] >> 16;
        mx = max(mx, max(lo16, hi16));
    }
#pragma unroll
    for (int off = 32; off; off >>= 1)
        mx = max(mx, (uint)__shfl_xor((int)mx, off));

    __syncthreads();

#pragma unroll
    for (int w = 0; w < 32; w++) {
        uint d0 = mx - (kw[w] & 0xFFFFu);
        uint d1 = mx - (kw[w] >> 16);
        if (d0 < HWIN) atomicAdd(&hist[wv][d0], 1u);
        if (d1 < HWIN) atomicAdd(&hist[wv][d1], 1u);
    }
    __syncthreads();

    const uint c0 = hist[wv][lane * 4 + 0];
    const uint c1 = hist[wv][lane * 4 + 1];
    const uint c2 = hist[wv][lane * 4 + 2];
    const uint c3 = hist[wv][lane * 4 + 3];
    const uint seg = c0 + c1 + c2 + c3;
    uint scan = seg;
#pragma unroll
    for (int d = 1; d < 64; d <<= 1) {
        uint y = (uint)__shfl_up((int)scan, d);
        if (lane >= d) scan += y;
    }
    const uint excl = scan - seg;
    const bool crossing = (excl < CANDN) && (scan >= CANDN);
    unsigned long long bal = __ballot(crossing);

    int t = 256;
    if (bal != 0ull) {
        const int srcLane = __ffsll(bal) - 1;
        int tloc = lane * 4;
        if (crossing) {
            uint cum = excl + c0;
            if (cum < CANDN) { tloc++; cum += c1;
                if (cum < CANDN) { tloc++; cum += c2;
                    if (cum < CANDN) { tloc++; } } }
        }
        t = __shfl(tloc, srcLane);
    }

    uint T;
    if (t <= 254) {
        T = mx - (uint)t;
    } else {
        // exact fallback: top-40 spread exceeds HWIN ulps (rare)
        uint lo = 0;
#pragma unroll
        for (int b = 15; b >= 0; b--) {
            uint trial = lo | (1u << b);
            int c = 0;
#pragma unroll
            for (int w = 0; w < 32; w++) {
                c += ((kw[w] & 0xFFFFu) >= trial) ? 1 : 0;
                c += ((kw[w] >> 16)     >= trial) ? 1 : 0;
            }
#pragma unroll
            for (int off = 32; off; off >>= 1) c += __shfl_xor(c, off);
            if (c >= CANDN) lo = trial;
        }
        T = lo;
    }

#pragma unroll
    for (int w = 0; w < 32; w++) {
        const uint lo16 = kw[w] & 0xFFFFu, hi16 = kw[w] >> 16;
        const int P0 = (w >> 2) * 512 + lane * 8 + (w & 3) * 2;  // u16 position
        if (lo16 >= T) {
            uint pos = atomicAdd(&ccnt[wv], 1u);
            if (pos < 64u) cand[wv][pos] = (uint)jdecode(P0);
        }
        if (hi16 >= T) {
            uint pos = atomicAdd(&ccnt[wv], 1u);
            if (pos < 64u) cand[wv][pos] = (uint)jdecode(P0 + 1);
        }
    }
    __syncthreads();
    const int m = (int)min(ccnt[wv], 64u);

    unsigned long long ukey = 0ull;
    if (lane < m) {
        const int j = (int)cand[wv][lane];
        const float4* kr = reinterpret_cast<const float4*>(kf + (size_t)j * DIM + h * DH);
        const float4* qr = reinterpret_cast<const float4*>(qsh[wv]);
        float s = 0.f;
#pragma unroll
        for (int d = 0; d < 16; d++) {
            float4 a = qr[d], bb = kr[d];
            s += a.x * bb.x; s += a.y * bb.y; s += a.z * bb.z; s += a.w * bb.w;
        }
        uint bits = __float_as_uint(s);
        uint s32 = (bits & 0x80000000u) ? ~bits : (bits | 0x80000000u);
        ukey = ((unsigned long long)s32 << 12) | (unsigned long long)(4095 - j);
    }

#pragma unroll
    for (int k = 2; k <= 64; k <<= 1) {
#pragma unroll
        for (int jj = k >> 1; jj > 0; jj >>= 1) {
            unsigned long long o = __shfl_xor(ukey, jj);
            bool keepMax = ((lane & jj) != 0) ^ ((lane & k) != 0);
            ukey = keepMax ? (ukey > o ? ukey : o) : (ukey < o ? ukey : o);
        }
    }

    const int rank = 63 - lane;
    const int jsel = 4095 - (int)(ukey & 0xFFFull);
    uint s32b = (uint)(ukey >> 12);
    uint fb = (s32b & 0x80000000u) ? (s32b ^ 0x80000000u) : ~s32b;
    const float sc = __uint_as_float(fb);
    const float stop = __shfl(sc, 63);

    float e = (rank < TOPK) ? __expf((sc - stop) * ATT_SCALE) : 0.f;
    float esum = e;
#pragma unroll
    for (int off = 32; off; off >>= 1) esum += __shfl_xor(esum, off);
    const float p = e / esum;

    if (rank < TOPK) {
        pw[wv][rank] = p; jw[wv][rank] = jsel;
        pval[(size_t)row * 32 + rank] = p;
        pidx[(size_t)row * 32 + rank] = jsel;
    }
    __syncthreads();

    float a = 0.f;
#pragma unroll
    for (int c = 0; c < TOPK; c++)
        a += pw[wv][c] * vf[(size_t)jw[wv][c] * DIM + h * DH + lane];
    ctxb[(size_t)i * DIM + h * DH + lane] = f2bf(a);
}

// ---------------------------------------------------------------------------
// attn_ln: merged launch.
//   blockIdx.x in [0,4096):    attn_write — 4 rows per block, LDS-staged
//                              (zero + scatter in LDS, one global write pass).
//   blockIdx.x in [4096,5120): LayerNorm — 4 rows per block, one wave per row.
// Independent outputs (attnF vs outF); both run after oproj/select.
// ---------------------------------------------------------------------------
__global__ __launch_bounds__(256) void attn_ln(
    const float* __restrict__ pval, const int* __restrict__ pidx,
    float* __restrict__ attnF,
    float* __restrict__ resb, const float* __restrict__ g,
    const float* __restrict__ b)
{
    __shared__ __align__(16) float rb[4][N_TOK];
    const int tid = threadIdx.x;

    if (blockIdx.x < 4096) {
        const int r0 = blockIdx.x * 4;

        float4* rb4 = reinterpret_cast<float4*>(&rb[0][0]);
        const float4 z = {0.f, 0.f, 0.f, 0.f};
#pragma unroll
        for (int t = 0; t < 16; t++) rb4[t * 256 + tid] = z;
        __syncthreads();
        if (tid < 4 * TOPK) {
            const int w = tid / TOPK, c = tid % TOPK;
            rb[w][pidx[(size_t)(r0 + w) * 32 + c]] = pval[(size_t)(r0 + w) * 32 + c];
        }
        __syncthreads();
#pragma unroll
        for (int w = 0; w < 4; w++) {
            float4* grow = reinterpret_cast<float4*>(attnF + (size_t)(r0 + w) * N_TOK);
#pragma unroll
            for (int t = 0; t < 4; t++)
                grow[t * 256 + tid] = rb4[w * 1024 + t * 256 + tid];
        }
    } else {
        const int lane = tid & 63;
        const int wv   = tid >> 6;
        const int i    = (blockIdx.x - 4096) * 4 + wv;
        float4* rowp = reinterpret_cast<float4*>(resb + (size_t)i * DIM);
        float4 x = rowp[lane];
        float s  = x.x + x.y + x.z + x.w;
        float sq = x.x * x.x + x.y * x.y + x.z * x.z + x.w * x.w;
#pragma unroll
        for (int off = 32; off; off >>= 1) {
            s  += __shfl_xor(s, off);
            sq += __shfl_xor(sq, off);
        }
        const float mu  = s * (1.f / DIM);
        const float var = sq * (1.f / DIM) - mu * mu;
        const float rstd = rsqrtf(var + LN_EPS);
        const int col = lane * 4;
        float4 o;
        o.x = (x.x - mu) * rstd * g[col + 0] + b[col + 0];
        o.y = (x.y - mu) * rstd * g[col + 1] + b[col + 1];
        o.z = (x.z - mu) * rstd * g[col + 2] + b[col + 2];
        o.w = (x.w - mu) * rstd * g[col + 3] + b[col + 3];
        rowp[lane] = o;
    }
}

// ---------------------------------------------------------------------------
extern "C" void kernel_launch(void* const* d_in, const int* in_sizes, int n_in,
                              void* d_out, int out_size, void* d_ws, size_t ws_size,
                              hipStream_t stream)
{
    const float* key_in   = (const float*)d_in[0];
    const float* value_in = (const float*)d_in[1];
    const float* query_in = (const float*)d_in[2];
    const float* Wq = (const float*)d_in[3];
    const float* bq = (const float*)d_in[4];
    const float* Wk = (const float*)d_in[5];
    const float* bk = (const float*)d_in[6];
    const float* Wv = (const float*)d_in[7];
    const float* bv = (const float*)d_in[8];
    const float* Wo = (const float*)d_in[9];
    const float* bo = (const float*)d_in[10];
    const float* ln_g = (const float*)d_in[11];
    const float* ln_b = (const float*)d_in[12];

    float* outF  = (float*)d_out;                     // (N, D) fp32
    float* attnF = outF + (size_t)N_TOK * DIM;        // (H, N, N) fp32

    // Large scratch carved inside the attn output region (all consumed before
    // attn_ln overwrites it; attn_ln runs last).
    const size_t SC = 33554432;               // 2 ushorts per attn float slot
    ushort* sb   = (ushort*)attnF;            // u16 sortable keys (128 MB)
    float*  qf   = attnF + SC;
    float*  kf   = attnF + SC + 1048576;
    float*  vf   = attnF + SC + 2097152;
    ushort* qb   = (ushort*)(attnF + SC + 3145728);
    ushort* kb   = (ushort*)(attnF + SC + 3670016);
    ushort* ctxb = (ushort*)(attnF + SC + 4194304);

    // d_ws: pval/pidx only (4 MB)
    float*  pval    = (float*)d_ws;                     // 2 MB
    int*    pidx    = (int*)d_ws + 524288;              // 2 MB

    front_kernel<<<dim3(12, 64), 256, 0, stream>>>(
        query_in, key_in, value_in, Wq, bq, Wk, bk, Wv, bv,
        qf, kf, qb, kb, vf);

    scores_kernel<<<dim3(32, 32, NH), 256, 0, stream>>>(qb, kb, sb);
    select_kernel<<<dim3(N_TOK * NH / 4), 256, 0, stream>>>(
        sb, qf, kf, vf, pval, pidx, ctxb);

    oproj_kernel<<<dim3(4, 64), 256, 0, stream>>>(ctxb, Wo, bo, query_in, outF);

    attn_ln<<<dim3(4096 + 1024), 256, 0, stream>>>(
        pval, pidx, attnF, outF, ln_g, ln_b);
}